// Round 9
// baseline (119.154 us; speedup 1.0000x reference)
//
#include <hip/hip_runtime.h>
#include <stdint.h>

#define AQ_MAX 15.0f
#define BN_EPS 1e-5f

// ---------------------------------------------------------------------------
// Merged prep: per-output-channel int4 symmetric weight fake-quant + BN fold.
// P layout (floats): wq1[32*28]@0 wq2[288]@896 wq3[1536]@1184 wq4[432]@2720
//   wq5[3072]@3152 | inv1@6224 beta1@6256 inv2@6288 beta2@6320 inv3@6352
//   beta3@6400 inv4@6448 beta4@6496 inv5@6544 beta5@6608 (end 6672)
// ---------------------------------------------------------------------------
__global__ __launch_bounds__(64) void prep_all(
    const float* __restrict__ wA, const float* __restrict__ gA,
    const float* __restrict__ bA, const float* __restrict__ mA,
    const float* __restrict__ vA,
    const float* __restrict__ wB, const float* __restrict__ gB,
    const float* __restrict__ bB, const float* __restrict__ mB,
    const float* __restrict__ vB,
    const float* __restrict__ wC, const float* __restrict__ gC,
    const float* __restrict__ bC, const float* __restrict__ mC,
    const float* __restrict__ vC,
    const float* __restrict__ wD, const float* __restrict__ gD,
    const float* __restrict__ bD, const float* __restrict__ mD,
    const float* __restrict__ vD,
    const float* __restrict__ wE, const float* __restrict__ gE,
    const float* __restrict__ bE, const float* __restrict__ mE,
    const float* __restrict__ vE,
    float* __restrict__ P) {
  int blk = blockIdx.x, t = threadIdx.x;
  const float *w, *g, *b, *m, *v;
  float *wq, *inv, *beta;
  int K, KP, c;
  if (blk < 32) {
    c = blk; w = wA; g = gA; b = bA; m = mA; v = vA; K = 27; KP = 28;
    wq = P + 0; inv = P + 6224; beta = P + 6256;
  } else if (blk < 64) {
    c = blk - 32; w = wB; g = gB; b = bB; m = mB; v = vB; K = 9; KP = 9;
    wq = P + 896; inv = P + 6288; beta = P + 6320;
  } else if (blk < 112) {
    c = blk - 64; w = wC; g = gC; b = bC; m = mC; v = vC; K = 32; KP = 32;
    wq = P + 1184; inv = P + 6352; beta = P + 6400;
  } else if (blk < 160) {
    c = blk - 112; w = wD; g = gD; b = bD; m = mD; v = vD; K = 9; KP = 9;
    wq = P + 2720; inv = P + 6448; beta = P + 6496;
  } else {
    c = blk - 160; w = wE; g = gE; b = bE; m = mE; v = vE; K = 48; KP = 48;
    wq = P + 3152; inv = P + 6544; beta = P + 6608;
  }
  const float* wc = w + (size_t)c * K;
  float a = (t < K) ? fabsf(wc[t]) : 0.0f;
#pragma unroll
  for (int off = 32; off >= 1; off >>= 1) a = fmaxf(a, __shfl_xor(a, off));
  float s = fmaxf(a / 7.0f, 1e-8f);
  if (t < K) {
    float q = rintf(wc[t] / s);  // round half-to-even, same as jnp.round
    q = fminf(7.0f, fmaxf(-7.0f, q));
    wq[(size_t)c * KP + t] = q * s;
  } else if (t < KP) {
    wq[(size_t)c * KP + t] = 0.0f;
  }
  if (t == 0) {
    float iv = g[c] / sqrtf(v[c] + BN_EPS);
    inv[c] = iv;
    beta[c] = b[c] - m[c] * iv;
  }
}

// ---------------------------------------------------------------------------
// Stage 1 v5: conv 3x3 s2 p0, 3->32, fp32 -> uint4 codes [8,32,255,512(pad)].
// 4 px/thread + parity double-buffered s_load weights: next-oc loads issued
// inside the current body between sched_barrier(0) fences, so each body's
// entry lgkmcnt wait is on ~500-cycle-old loads (free).
// ---------------------------------------------------------------------------
#define S1_ROW(W, S)                                              \
  {                                                               \
    float wv0 = W[(S)*3], wv1 = W[(S)*3 + 1], wv2 = W[(S)*3 + 2]; \
    a0 = fmaf(r[S][0], wv0, a0); a1 = fmaf(r[S][2], wv0, a1);     \
    a2 = fmaf(r[S][4], wv0, a2); a3 = fmaf(r[S][6], wv0, a3);     \
    a0 = fmaf(r[S][1], wv1, a0); a1 = fmaf(r[S][3], wv1, a1);     \
    a2 = fmaf(r[S][5], wv1, a2); a3 = fmaf(r[S][7], wv1, a3);     \
    a0 = fmaf(r[S][2], wv2, a0); a1 = fmaf(r[S][4], wv2, a1);     \
    a2 = fmaf(r[S][6], wv2, a2); a3 = fmaf(r[S][8], wv2, a3);     \
  }

#define S1_LOADW(W, IV, BT, OCIDX)                              \
  {                                                             \
    _Pragma("unroll") for (int tq = 0; tq < 7; tq++) {          \
      float4 f = *(const float4*)(P + (OCIDX)*28 + 4 * tq);     \
      W[4*tq] = f.x; W[4*tq+1] = f.y;                           \
      W[4*tq+2] = f.z; W[4*tq+3] = f.w;                         \
    }                                                           \
    IV = P[6224 + (OCIDX)];                                     \
    BT = P[6256 + (OCIDX)];                                     \
  }

#define S1_BODY(W, IV, BT, OCIDX, ...)                                     \
  {                                                                        \
    float a0 = 0, a1 = 0, a2 = 0, a3 = 0;                                  \
    S1_ROW(W, 0);                                                          \
    __builtin_amdgcn_sched_barrier(0);                                     \
    __VA_ARGS__                                                            \
    __builtin_amdgcn_sched_barrier(0);                                     \
    S1_ROW(W, 1); S1_ROW(W, 2); S1_ROW(W, 3); S1_ROW(W, 4);                \
    S1_ROW(W, 5); S1_ROW(W, 6); S1_ROW(W, 7); S1_ROW(W, 8);                \
    float y0 = fmaf(a0, IV, BT), y1 = fmaf(a1, IV, BT);                    \
    float y2 = fmaf(a2, IV, BT), y3 = fmaf(a3, IV, BT);                    \
    uint32_t q0 = (uint32_t)fminf(AQ_MAX, fmaxf(0.0f, rintf(y0 / s1)));    \
    uint32_t q1 = (uint32_t)fminf(AQ_MAX, fmaxf(0.0f, rintf(y1 / s1)));    \
    uint32_t q2 = (uint32_t)fminf(AQ_MAX, fmaxf(0.0f, rintf(y2 / s1)));    \
    uint32_t q3 = (uint32_t)fminf(AQ_MAX, fmaxf(0.0f, rintf(y3 / s1)));    \
    *(uint32_t*)(out + obase + (size_t)(OCIDX) * (255 * 512)) =            \
        q0 | (q1 << 8) | (q2 << 16) | (q3 << 24);                          \
  }

__global__ __launch_bounds__(256) void stage1_kernel(
    const float* __restrict__ x, const float* __restrict__ P,
    const float* __restrict__ s1p, uint8_t* __restrict__ out) {
  int tid = blockIdx.x * 256 + threadIdx.x;  // 8*255*128 = 261,120 threads
  int gx = tid & 127;
  int t2 = tid >> 7;
  int oy = t2 % 255;
  int n = t2 / 255;
  float s1 = *s1p;
  int ix0 = gx * 8, iy = 2 * oy;
  bool tailok = (ix0 + 8) < 1024;  // tap 8 only feeds the dead pad px
  float r[9][9];
#pragma unroll
  for (int ic = 0; ic < 3; ic++)
#pragma unroll
    for (int kh = 0; kh < 3; kh++) {
      const float* bp = x + (((size_t)(n * 3 + ic)) * 512 + (iy + kh)) * 1024 + ix0;
      float4 f0 = *(const float4*)bp;
      float4 f1 = *(const float4*)(bp + 4);
      int s = ic * 3 + kh;
      r[s][0] = f0.x; r[s][1] = f0.y; r[s][2] = f0.z; r[s][3] = f0.w;
      r[s][4] = f1.x; r[s][5] = f1.y; r[s][6] = f1.z; r[s][7] = f1.w;
      r[s][8] = tailok ? bp[8] : 0.0f;
    }
  size_t obase = (((size_t)n * 32) * 255 + oy) * 512 + gx * 4;
  float wA[28], wB[28], ivA, btA, ivB, btB;
  S1_LOADW(wA, ivA, btA, 0);
#pragma unroll
  for (int i = 0; i < 32; i += 2) {
    S1_BODY(wA, ivA, btA, i, { S1_LOADW(wB, ivB, btB, i + 1); });
    S1_BODY(wB, ivB, btB, i + 1, {
      if (i + 2 < 32) S1_LOADW(wA, ivA, btA, i + 2);
    });
  }
}

// ---------------------------------------------------------------------------
// Depthwise 3x3 s2 p1, codes in -> codes out. 4 output px/thread. (unchanged)
// ---------------------------------------------------------------------------
template <int C, int IH, int IWL, int IWP, int OH, int OW>
__global__ __launch_bounds__(256) void dw_kernel(
    const uint8_t* __restrict__ in, const float* __restrict__ wq,
    const float* __restrict__ inv, const float* __restrict__ beta,
    const float* __restrict__ sin_p, const float* __restrict__ sout_p,
    uint8_t* __restrict__ out) {
  constexpr int GX = OW / 4;
  int tid = blockIdx.x * 256 + threadIdx.x;
  int oxg = tid % GX;
  int t2 = tid / GX;
  int oy = t2 % OH;
  int t3 = t2 / OH;
  int c = __builtin_amdgcn_readfirstlane(t3 % C);
  int n = __builtin_amdgcn_readfirstlane(t3 / C);
  float s_in = *sin_p, s_out = *sout_p;
  const float* wc = wq + c * 9;  // uniform -> s_load
  float w[9];
#pragma unroll
  for (int j = 0; j < 9; j++) w[j] = wc[j];
  float iv = inv[c], bt = beta[c];
  int c0 = oxg * 8;
  const uint8_t* chan = in + ((size_t)(n * C + c)) * IH * IWP;
  float xr[3][9];
#pragma unroll
  for (int kh = 0; kh < 3; kh++) {
    int iy = 2 * oy + kh - 1;
    if (iy >= 0 && iy < IH) {
      const uint8_t* rp = chan + (size_t)iy * IWP;
      uint2 u = *(const uint2*)(rp + c0);
      xr[kh][0] = (oxg > 0) ? (float)rp[c0 - 1] : 0.0f;
#pragma unroll
      for (int j = 0; j < 4; j++) xr[kh][1 + j] = (float)((u.x >> (8 * j)) & 255u);
#pragma unroll
      for (int j = 0; j < 4; j++) xr[kh][5 + j] = (float)((u.y >> (8 * j)) & 255u);
      if (IWL < IWP && oxg == GX - 1) xr[kh][8] = 0.0f;
    } else {
#pragma unroll
      for (int j = 0; j < 9; j++) xr[kh][j] = 0.0f;
    }
  }
#pragma unroll
  for (int kh = 0; kh < 3; kh++)
#pragma unroll
    for (int j = 0; j < 9; j++) xr[kh][j] *= s_in;
  float acc[4] = {0, 0, 0, 0};
#pragma unroll
  for (int kh = 0; kh < 3; kh++)
#pragma unroll
    for (int kw = 0; kw < 3; kw++) {
      float wv = w[kh * 3 + kw];
#pragma unroll
      for (int p = 0; p < 4; p++) acc[p] = fmaf(xr[kh][2 * p + kw], wv, acc[p]);
    }
  uint32_t pack = 0;
#pragma unroll
  for (int p = 0; p < 4; p++) {
    float y = fmaf(acc[p], iv, bt);
    float q = fminf(AQ_MAX, fmaxf(0.0f, rintf(y / s_out)));
    pack |= ((uint32_t)q) << (8 * p);
  }
  *(uint32_t*)(out + ((size_t)(n * C + c) * OH + oy) * OW + c0 / 2) = pack;
}

// ---------------------------------------------------------------------------
// Pointwise 1x1, oc-chunked. 2 px/thread. DB=true: parity double-buffered
// s_load weights. NOTE: macro param is OCIDX — round-8 bug was a param named
// OC shadowing the template OC in the output address (absmax 1.5).
// ---------------------------------------------------------------------------
#define PW_LOADW(W, IV, BT, OCIDX)                                   \
  {                                                                  \
    _Pragma("unroll") for (int tq = 0; tq < IC / 4; tq++) {          \
      float4 f = *(const float4*)(Pw + (size_t)(OCIDX)*IC + 4 * tq); \
      W[4*tq] = f.x; W[4*tq+1] = f.y;                                \
      W[4*tq+2] = f.z; W[4*tq+3] = f.w;                              \
    }                                                                \
    IV = Pinv[(OCIDX)];                                              \
    BT = Pbeta[(OCIDX)];                                             \
  }

#define PW_BODY(W, IV, BT, OCIDX, ...)                                       \
  {                                                                          \
    float a0 = 0, a1 = 0;                                                    \
    _Pragma("unroll") for (int ic = 0; ic < 8; ic++) {                       \
      a0 = fmaf(xa[ic], W[ic], a0);                                          \
      a1 = fmaf(xb[ic], W[ic], a1);                                          \
    }                                                                        \
    __builtin_amdgcn_sched_barrier(0);                                       \
    __VA_ARGS__                                                              \
    __builtin_amdgcn_sched_barrier(0);                                       \
    _Pragma("unroll") for (int ic = 8; ic < IC; ic++) {                      \
      a0 = fmaf(xa[ic], W[ic], a0);                                          \
      a1 = fmaf(xb[ic], W[ic], a1);                                          \
    }                                                                        \
    float y0 = fmaf(a0, IV, BT), y1 = fmaf(a1, IV, BT);                      \
    float q0 = fminf(AQ_MAX, fmaxf(0.0f, rintf(y0 / s_out)));                \
    float q1 = fminf(AQ_MAX, fmaxf(0.0f, rintf(y1 / s_out)));                \
    if (FINAL) {                                                             \
      float2 o;                                                              \
      o.x = q0 * s_out; o.y = q1 * s_out;                                    \
      *(float2*)((float*)outv + ((size_t)n * OC + (OCIDX)) * HW + px0) = o;  \
    } else {                                                                 \
      uint16_t pk = (uint16_t)((uint32_t)q0 | ((uint32_t)q1 << 8));          \
      *(uint16_t*)((uint8_t*)outv + ((size_t)n * OC + (OCIDX)) * HW + px0) = pk; \
    }                                                                        \
  }

template <int IC, int OC, int CHUNK, int HW, bool FINAL, bool DB>
__global__ __launch_bounds__(256) void pw_kernel(
    const uint8_t* __restrict__ in, const float* __restrict__ Pw,
    const float* __restrict__ Pinv, const float* __restrict__ Pbeta,
    const float* __restrict__ sin_p, const float* __restrict__ sout_p,
    void* __restrict__ outv) {
  constexpr int NCH = OC / CHUNK;
  constexpr int PG = HW / 2;
  int bid = blockIdx.x;
  int chunk = bid % NCH;
  int pb = bid / NCH;
  int tpx = pb * 256 + threadIdx.x;
  int px0 = (tpx % PG) * 2;
  int n = __builtin_amdgcn_readfirstlane(tpx / PG);
  float s_in = *sin_p, s_out = *sout_p;
  const uint8_t* ib = in + (size_t)n * IC * HW + px0;
  float xa[IC], xb[IC];
#pragma unroll
  for (int ic = 0; ic < IC; ic++) {
    uint16_t u = *(const uint16_t*)(ib + (size_t)ic * HW);
    xa[ic] = (float)(u & 255u) * s_in;
    xb[ic] = (float)(u >> 8) * s_in;
  }
  int oc0 = chunk * CHUNK;
  if (DB) {
    float wA[IC], wB[IC], ivA, btA, ivB, btB;
    PW_LOADW(wA, ivA, btA, oc0);
#pragma unroll
    for (int i = 0; i < CHUNK; i += 2) {
      PW_BODY(wA, ivA, btA, oc0 + i, { PW_LOADW(wB, ivB, btB, oc0 + i + 1); });
      PW_BODY(wB, ivB, btB, oc0 + i + 1, {
        if (i + 2 < CHUNK) PW_LOADW(wA, ivA, btA, oc0 + i + 2);
      });
    }
  } else {
#pragma unroll 2
    for (int oc = oc0; oc < oc0 + CHUNK; oc++) {
      const float* wp = Pw + (size_t)oc * IC;  // uniform -> s_load
      float w[IC];
#pragma unroll
      for (int ic = 0; ic < IC; ic++) w[ic] = wp[ic];
      float a0 = 0, a1 = 0;
#pragma unroll
      for (int ic = 0; ic < IC; ic++) {
        a0 = fmaf(xa[ic], w[ic], a0);
        a1 = fmaf(xb[ic], w[ic], a1);
      }
      float iv = Pinv[oc], bt = Pbeta[oc];
      float y0 = fmaf(a0, iv, bt), y1 = fmaf(a1, iv, bt);
      float q0 = fminf(AQ_MAX, fmaxf(0.0f, rintf(y0 / s_out)));
      float q1 = fminf(AQ_MAX, fmaxf(0.0f, rintf(y1 / s_out)));
      if (FINAL) {
        float2 o;
        o.x = q0 * s_out; o.y = q1 * s_out;
        *(float2*)((float*)outv + ((size_t)n * OC + oc) * HW + px0) = o;
      } else {
        uint16_t pk = (uint16_t)((uint32_t)q0 | ((uint32_t)q1 << 8));
        *(uint16_t*)((uint8_t*)outv + ((size_t)n * OC + oc) * HW + px0) = pk;
      }
    }
  }
}

extern "C" void kernel_launch(void* const* d_in, const int* in_sizes, int n_in,
                              void* d_out, int out_size, void* d_ws, size_t ws_size,
                              hipStream_t stream) {
  const float* x    = (const float*)d_in[0];
  const float* w1   = (const float*)d_in[1];
  const float* g1   = (const float*)d_in[2];
  const float* b1   = (const float*)d_in[3];
  const float* m1   = (const float*)d_in[4];
  const float* v1   = (const float*)d_in[5];
  const float* s1   = (const float*)d_in[6];
  const float* wdw1 = (const float*)d_in[7];
  const float* g2   = (const float*)d_in[8];
  const float* b2   = (const float*)d_in[9];
  const float* m2   = (const float*)d_in[10];
  const float* v2   = (const float*)d_in[11];
  const float* s2   = (const float*)d_in[12];
  const float* wpw1 = (const float*)d_in[13];
  const float* g3   = (const float*)d_in[14];
  const float* b3   = (const float*)d_in[15];
  const float* m3   = (const float*)d_in[16];
  const float* v3   = (const float*)d_in[17];
  const float* s3   = (const float*)d_in[18];
  const float* wdw2 = (const float*)d_in[19];
  const float* g4   = (const float*)d_in[20];
  const float* b4   = (const float*)d_in[21];
  const float* m4   = (const float*)d_in[22];
  const float* v4   = (const float*)d_in[23];
  const float* s4   = (const float*)d_in[24];
  const float* wpw2 = (const float*)d_in[25];
  const float* g5   = (const float*)d_in[26];
  const float* b5   = (const float*)d_in[27];
  const float* m5   = (const float*)d_in[28];
  const float* v5   = (const float*)d_in[29];
  const float* s5   = (const float*)d_in[30];

  float* P = (float*)d_ws;
  float* wq2  = P + 896;
  float* wq3  = P + 1184;
  float* wq4  = P + 2720;
  float* wq5  = P + 3152;
  float* inv2 = P + 6288, *beta2 = P + 6320;
  float* inv3 = P + 6352, *beta3 = P + 6400;
  float* inv4 = P + 6448, *beta4 = P + 6496;
  float* inv5 = P + 6544, *beta5 = P + 6608;

  uint8_t* ws8 = (uint8_t*)d_ws;
  uint8_t* x1 = ws8 + 32768;            // [8,32,255,512] codes: 33,423,360 B
  uint8_t* x2 = x1 + 33423360;          // [8,32,128,256]:  8,388,608 B
  uint8_t* x3 = x2 + 8388608;           // [8,48,128,256]: 12,582,912 B
  uint8_t* x4 = ws8 + 32768;            // [8,48,64,128]: aliases x1 (dead)

  prep_all<<<224, 64, 0, stream>>>(w1, g1, b1, m1, v1,
                                   wdw1, g2, b2, m2, v2,
                                   wpw1, g3, b3, m3, v3,
                                   wdw2, g4, b4, m4, v4,
                                   wpw2, g5, b5, m5, v5, P);

  // Stage 1: 8*255*128 threads, 4 px each
  stage1_kernel<<<1020, 256, 0, stream>>>(x, P, s1, x1);
  // dw1: 32ch, 255x511(512) -> 128x256
  dw_kernel<32, 255, 511, 512, 128, 256>
      <<<8192, 256, 0, stream>>>(x1, wq2, inv2, beta2, s1, s2, x2);
  // pw1: 32->48 @128x256, chunk 24 (2 chunks), dual-buffered weights
  pw_kernel<32, 48, 24, 32768, false, true>
      <<<1024, 256, 0, stream>>>(x2, wq3, inv3, beta3, s2, s3, x3);
  // dw2: 48ch, 128x256 -> 64x128
  dw_kernel<48, 128, 256, 256, 64, 128>
      <<<3072, 256, 0, stream>>>(x3, wq4, inv4, beta4, s3, s4, x4);
  // pw2: 48->64 @64x128 -> fp32, chunk 8 (8 chunks), single-buffer
  pw_kernel<48, 64, 8, 8192, true, false>
      <<<1024, 256, 0, stream>>>(x4, wq5, inv5, beta5, s4, s5, (float*)d_out);
}